// Round 5
// baseline (750.276 us; speedup 1.0000x reference)
//
#include <hip/hip_runtime.h>

#define NEG_SLOPE 0.2f

static const int B = 4, N = 50000, R = 100000, E = 1600000;
static const int WI_CAP = 131072;   // wi compact/pairs capacity (expected ~33k)
static const int X2_CAP = 4096;     // x2 edge list capacity (expected ~64)

// flagsR bits: 1 = R2 (rows needed for t2), 2 = R1 (rows needed for t1)

// ---------- markA: wi edges with row >= N-2 -> flagsR bit0 + x2 edge list ------
__global__ void markA(const int4* __restrict__ wi_rows4, const int* __restrict__ wi_cols,
                      const float* __restrict__ wi_val,
                      int* __restrict__ flagsR, int2* __restrict__ x2list,
                      int* __restrict__ x2tail, int e4) {
    int base = blockIdx.x * (blockDim.x * 4) + threadIdx.x;
#pragma unroll
    for (int k = 0; k < 4; ++k) {
        int i = base + k * blockDim.x;
        if (i >= e4) continue;
        int4 r = wi_rows4[i];
        int rr[4] = {r.x, r.y, r.z, r.w};
#pragma unroll
        for (int j = 0; j < 4; ++j) {
            if (rr[j] >= N - 2) {
                int ed = i * 4 + j;
                int col = wi_cols[ed];
                flagsR[col] = 1;
                int pos = atomicAdd(x2tail, 1);
                if (pos < X2_CAP)
                    x2list[pos] = make_int2(col * 2 + (rr[j] - (N - 2)),
                                            __float_as_int(wi_val[ed]));
            }
        }
    }
}

// ---------- markB: w edges with flagged row -> flagN1[col] ----------
__global__ void markB(const int4* __restrict__ w_rows4, const int* __restrict__ w_cols,
                      const int* __restrict__ flagsR, int* __restrict__ flagN1, int e4) {
    int base = blockIdx.x * (blockDim.x * 4) + threadIdx.x;
#pragma unroll
    for (int k = 0; k < 4; ++k) {
        int i = base + k * blockDim.x;
        if (i >= e4) continue;
        int4 r = w_rows4[i];
        int rr[4] = {r.x, r.y, r.z, r.w};
#pragma unroll
        for (int j = 0; j < 4; ++j)
            if (flagsR[rr[j]]) flagN1[w_cols[i * 4 + j]] = 1;
    }
}

// ---- markC_wi: wi edges with flagN1 row -> flagsR bit1, wi hist, wi compact ----
__global__ void markC_wi(const int4* __restrict__ wi_rows4, const int* __restrict__ wi_cols,
                         const float* __restrict__ wi_val, const float* __restrict__ diag1,
                         const int* __restrict__ flagN1,
                         int* __restrict__ flagsR, int* __restrict__ wi_cnt,
                         int2* __restrict__ wi_rc, float* __restrict__ wi_cf,
                         int* __restrict__ witail, int e4) {
    int lane = threadIdx.x & 63;
    int base = blockIdx.x * (blockDim.x * 4) + threadIdx.x;
#pragma unroll
    for (int k = 0; k < 4; ++k) {
        int i = base + k * blockDim.x;
        int4 r = make_int4(-1, -1, -1, -1);
        if (i < e4) r = wi_rows4[i];
        int rr[4] = {r.x, r.y, r.z, r.w};
#pragma unroll
        for (int j = 0; j < 4; ++j) {
            bool pass = (rr[j] >= 0) && (flagN1[rr[j]] != 0);
            int col = 0; float cf = 0.f;
            if (pass) {
                int ed = i * 4 + j;
                col = wi_cols[ed];
                cf = wi_val[ed] * diag1[col];
                atomicAdd(&wi_cnt[rr[j]], 1);
                flagsR[col] |= 2;      // benign same-value RMW race
            }
            unsigned long long m = __ballot(pass);
            if (m) {
                int leader = __ffsll((unsigned long long)m) - 1;
                int cnt = __popcll(m);
                int b0 = 0;
                if (lane == leader) b0 = atomicAdd(witail, cnt);
                b0 = __shfl(b0, leader);
                if (pass) {
                    int pos = b0 + __popcll(m & ((1ull << lane) - 1));
                    if (pos < WI_CAP) { wi_rc[pos] = make_int2(rr[j], col); wi_cf[pos] = cf; }
                }
            }
        }
    }
}

// ---------- whist: w edges with flagsR row -> w hist + (row,eid) compact ----------
__global__ void whist(const int4* __restrict__ w_rows4, const int* __restrict__ flagsR,
                      int* __restrict__ w_cnt, int2* __restrict__ w_compact,
                      int* __restrict__ wtail, int e4) {
    int lane = threadIdx.x & 63;
    int base = blockIdx.x * (blockDim.x * 4) + threadIdx.x;
#pragma unroll
    for (int k = 0; k < 4; ++k) {
        int i = base + k * blockDim.x;
        int4 r = make_int4(-1, -1, -1, -1);
        if (i < e4) r = w_rows4[i];
        int rr[4] = {r.x, r.y, r.z, r.w};
#pragma unroll
        for (int j = 0; j < 4; ++j) {
            bool pass = (rr[j] >= 0) && (flagsR[rr[j]] != 0);
            if (pass) atomicAdd(&w_cnt[rr[j]], 1);
            unsigned long long m = __ballot(pass);
            if (m) {
                int leader = __ffsll((unsigned long long)m) - 1;
                int b0 = 0;
                if (lane == leader) b0 = atomicAdd(wtail, __popcll(m));
                b0 = __shfl(b0, leader);
                if (pass)
                    w_compact[b0 + __popcll(m & ((1ull << lane) - 1))] =
                        make_int2(rr[j], i * 4 + j);
            }
        }
    }
}

// ------- segment base assignment for both CSRs in one dispatch (order-free) -----
__global__ void assign_offsets2(const int* __restrict__ cntA, int nA, int* __restrict__ offA,
                                const int* __restrict__ cntB, int nB, int* __restrict__ offB,
                                int* __restrict__ gcur) {
    int nBlocksA = (nA + 255) / 256;
    bool isA = (int)blockIdx.x < nBlocksA;
    const int* cnt = isA ? cntA : cntB;
    int* off = isA ? offA : offB;
    int n = isA ? nA : nB;
    int* gc = gcur + (isA ? 0 : 1);
    int blk = isA ? blockIdx.x : (blockIdx.x - nBlocksA);
    int i = blk * 256 + threadIdx.x;
    int tid = threadIdx.x;
    int v = (i < n) ? cnt[i] : 0;
    __shared__ int s[256];
    s[tid] = v;
    __syncthreads();
#pragma unroll
    for (int d = 1; d < 256; d <<= 1) {
        int t = (tid >= d) ? s[tid - d] : 0;
        __syncthreads();
        s[tid] += t;
        __syncthreads();
    }
    int incl = s[tid];
    __shared__ int base;
    if (tid == 255) base = atomicAdd(gc, incl);
    __syncthreads();
    if (i < n) off[i] = base + incl - v;
}

// ---------- place both CSRs from compacted records (grid-stride) ----------
__global__ void place_fused(const int2* __restrict__ w_compact, const int* __restrict__ wtail,
                            const int* __restrict__ w_cols, const float* __restrict__ w_val,
                            const int* __restrict__ w_off, int* __restrict__ w_cur,
                            const int2* __restrict__ wi_rc, const float* __restrict__ wi_cf,
                            const int* __restrict__ witail,
                            const int* __restrict__ wi_off, int* __restrict__ wi_cur,
                            int2* __restrict__ w_pairs, int2* __restrict__ wi_pairs) {
    int wt = *wtail;
    int wit = *witail; if (wit > WI_CAP) wit = WI_CAP;
    int total = wt + wit;
    int stride = gridDim.x * blockDim.x;
    for (int i = blockIdx.x * blockDim.x + threadIdx.x; i < total; i += stride) {
        if (i < wt) {
            int2 rc = w_compact[i];
            int col = w_cols[rc.y];
            float v = w_val[rc.y];
            int pos = w_off[rc.x] + atomicAdd(&w_cur[rc.x], 1);
            w_pairs[pos] = make_int2(col, __float_as_int(v));
        } else {
            int j = i - wt;
            int2 rc = wi_rc[j];
            int pos = wi_off[rc.x] + atomicAdd(&wi_cur[rc.x], 1);
            wi_pairs[pos] = make_int2(rc.y, __float_as_int(wi_cf[j]));
        }
    }
}

// ---------- gemm1: x [B][N][32] -> h1 [N][B][32] ----------
__global__ void gemm1_kernel(const float* __restrict__ x, const float* __restrict__ W,
                             float* __restrict__ h1) {
    __shared__ float sW[32 * 32];
    for (int i = threadIdx.x; i < 32 * 32; i += blockDim.x) sW[i] = W[i];
    __syncthreads();
    int n = blockIdx.x * blockDim.x + threadIdx.x;
    int b = blockIdx.y;
    if (n >= N) return;
    const float* xr = x + ((size_t)b * N + n) * 32;
    float acc[32];
#pragma unroll
    for (int c = 0; c < 32; ++c) acc[c] = 0.f;
#pragma unroll
    for (int k = 0; k < 32; ++k) {
        float xv = xr[k];
#pragma unroll
        for (int c = 0; c < 32; ++c) acc[c] += xv * sW[k * 32 + c];
    }
    float* o = h1 + ((size_t)n * B + b) * 32;
#pragma unroll
    for (int c = 0; c < 32; ++c) o[c] = acc[c];
}

// ---------- gemm2: x1 [N][B][32] (lrelu) -> h2 [N][B][16], flagN1-gated ----------
__global__ void gemm2_kernel(const float* __restrict__ x1, const float* __restrict__ W,
                             float* __restrict__ h2, const int* __restrict__ flagN1) {
    __shared__ float sW[32 * 16];
    for (int i = threadIdx.x; i < 32 * 16; i += blockDim.x) sW[i] = W[i];
    __syncthreads();
    int id = blockIdx.x * blockDim.x + threadIdx.x;   // n*B + b
    if (id >= N * B) return;
    if (!flagN1[id >> 2]) return;
    const float* xr = x1 + (size_t)id * 32;
    float acc[16];
#pragma unroll
    for (int c = 0; c < 16; ++c) acc[c] = 0.f;
#pragma unroll
    for (int k = 0; k < 32; ++k) {
        float xv = xr[k];
        xv = xv > 0.f ? xv : NEG_SLOPE * xv;
#pragma unroll
        for (int c = 0; c < 16; ++c) acc[c] += xv * sW[k * 16 + c];
    }
    float* o = h2 + (size_t)id * 16;
#pragma unroll
    for (int c = 0; c < 16; ++c) o[c] = acc[c];
}

// ---- flag-gated CSR gather, batch-inner layout [node][B][C], float4/thread ----
// FLAGBIT==0: pass if flag[row]!=0 ; else pass if (flag[row] & FLAGBIT)
template<int C, int FLAGBIT>
__global__ void gather_rows(const float* __restrict__ src, float* __restrict__ dst,
                            const int* __restrict__ off, const int* __restrict__ len,
                            const int2* __restrict__ pairs, const int* __restrict__ flag,
                            int nRows) {
    constexpr int C4 = C / 4;
    constexpr int TPR = C4 * B;
    constexpr int STRIDE = B * C4;        // float4 stride per source node block
    int tid = blockIdx.x * blockDim.x + threadIdx.x;
    int row = tid / TPR;
    int rem = tid - row * TPR;
    int c4 = rem & (C4 - 1);
    int b  = rem / C4;
    if (row >= nRows) return;
    int f = flag[row];
    if (FLAGBIT ? !(f & FLAGBIT) : !f) return;
    int s = off[row];
    int L = len[row];
    const float4* sb = (const float4*)src + b * C4 + c4;
    float4 acc = make_float4(0.f, 0.f, 0.f, 0.f);
    int i = s;
    int e4i = s + (L & ~3);
    for (; i < e4i; i += 4) {
        int2 p0 = pairs[i + 0];
        int2 p1 = pairs[i + 1];
        int2 p2 = pairs[i + 2];
        int2 p3 = pairs[i + 3];
        float4 s0 = sb[(size_t)p0.x * STRIDE];
        float4 s1 = sb[(size_t)p1.x * STRIDE];
        float4 s2 = sb[(size_t)p2.x * STRIDE];
        float4 s3 = sb[(size_t)p3.x * STRIDE];
        float v0 = __int_as_float(p0.y), v1 = __int_as_float(p1.y);
        float v2 = __int_as_float(p2.y), v3 = __int_as_float(p3.y);
        acc.x += v0 * s0.x + v1 * s1.x + v2 * s2.x + v3 * s3.x;
        acc.y += v0 * s0.y + v1 * s1.y + v2 * s2.y + v3 * s3.y;
        acc.z += v0 * s0.z + v1 * s1.z + v2 * s2.z + v3 * s3.z;
        acc.w += v0 * s0.w + v1 * s1.w + v2 * s2.w + v3 * s3.w;
    }
    for (; i < s + L; ++i) {
        int2 p = pairs[i];
        float4 sv = sb[(size_t)p.x * STRIDE];
        float v = __int_as_float(p.y);
        acc.x += v * sv.x; acc.y += v * sv.y; acc.z += v * sv.z; acc.w += v * sv.w;
    }
    ((float4*)dst)[(size_t)row * STRIDE + b * C4 + c4] = acc;
}

// ---------- x2 accumulation (tiny list) + heads, single block ----------
__global__ void x2final_heads(const float* __restrict__ t2, const int2* __restrict__ x2list,
                              const int* __restrict__ x2tail, const float* __restrict__ diag2,
                              const float* __restrict__ rw1, const float* __restrict__ rb1,
                              const float* __restrict__ rw2, const float* __restrict__ rb2,
                              float* __restrict__ out) {
    __shared__ float s[2 * B * 16];
    int tid = threadIdx.x;                // 64 threads: b = tid>>4, c = tid&15
    int b = tid >> 4, c = tid & 15;
    float acc0 = 0.f, acc1 = 0.f;
    int cnt = *x2tail; if (cnt > X2_CAP) cnt = X2_CAP;
    for (int i = 0; i < cnt; ++i) {
        int2 rec = x2list[i];
        int col = rec.x >> 1;
        float coef = __int_as_float(rec.y) * diag2[col];
        float v = t2[((size_t)col * B + b) * 16 + c] * coef;
        if (rec.x & 1) acc1 += v; else acc0 += v;
    }
    s[(b * 2 + 0) * 16 + c] = acc0;
    s[(b * 2 + 1) * 16 + c] = acc1;
    __syncthreads();
    if (tid < 2 * B) {
        int bb = tid >> 1, which = tid & 1;
        const float* w = which ? rw2 : rw1;
        float acc = which ? rb2[0] : rb1[0];
        const float* xr = s + (bb * 2 + which) * 16;
        for (int k = 0; k < 16; ++k) {
            float xv = xr[k];
            xv = xv > 0.f ? xv : NEG_SLOPE * xv;
            acc += xv * w[k];
        }
        out[tid] = acc;
    }
}

extern "C" void kernel_launch(void* const* d_in, const int* in_sizes, int n_in,
                              void* d_out, int out_size, void* d_ws, size_t ws_size,
                              hipStream_t stream) {
    const int*   w_rows  = (const int*)d_in[0];
    const int*   w_cols  = ((const int*)d_in[0]) + E;
    const float* w_val   = (const float*)d_in[1];
    const int*   wi_rows = (const int*)d_in[2];
    const int*   wi_cols = ((const int*)d_in[2]) + E;
    const float* wi_val  = (const float*)d_in[3];
    const float* x       = (const float*)d_in[4];
    const float* W1      = (const float*)d_in[5];
    const float* diag1   = (const float*)d_in[6];
    const float* W2      = (const float*)d_in[7];
    const float* diag2   = (const float*)d_in[8];
    const float* rw1     = (const float*)d_in[9];
    const float* rb1     = (const float*)d_in[10];
    const float* rw2     = (const float*)d_in[11];
    const float* rb2     = (const float*)d_in[12];
    float* out = (float*)d_out;

    // ---------------- workspace layout ----------------
    float* h1   = (float*)d_ws;                 // [N][B][32]; later aliased as x1
    float* treg = h1 + (size_t)B * N * 32;      // 12.8M floats: t1 [R][B][32];
                                                // early: compact buffers; later h2/t2
    int* ip = (int*)(treg + (size_t)B * R * 32);
    // zeroed block:
    int* w_cnt  = ip; ip += R;
    int* w_off  = ip; ip += R;
    int* w_cur  = ip; ip += R;
    int* wi_cnt = ip; ip += N;
    int* wi_off = ip; ip += N;
    int* wi_cur = ip; ip += N;
    int* flagsR = ip; ip += R;
    int* flagN1 = ip; ip += N;
    int* gcur   = ip; ip += 2;
    int* tails  = ip; ip += 4;   // [0]=wtail [1]=witail [2]=x2tail
    size_t zero_words = (size_t)(ip - w_cnt);
    // un-zeroed:
    int2* w_pairs  = (int2*)ip; ip += 2 * E;
    int2* wi_pairs = (int2*)ip; ip += 2 * WI_CAP;
    int2* x2list   = (int2*)ip; ip += 2 * X2_CAP;
    // compact buffers aliased inside treg (dead before t1 is written):
    int2*  w_compact = (int2*)treg;                                  // E entries
    int2*  wi_rc     = (int2*)(treg + (size_t)2 * E);                // WI_CAP entries
    float* wi_cf     = treg + (size_t)2 * E + (size_t)2 * WI_CAP;    // WI_CAP floats

    float* x1 = h1;                          // alias
    float* h2 = treg;                        // [N][B][16]
    float* t2 = treg + (size_t)B * N * 16;   // [R][B][16]

    const int blk = 256;
    const int e4 = E / 4;
    const int scanGrid = (e4 + blk * 4 - 1) / (blk * 4);

    hipMemsetAsync(w_cnt, 0, zero_words * sizeof(int), stream);

    // ---- frontier + CSR build ----
    markA<<<scanGrid, blk, 0, stream>>>((const int4*)wi_rows, wi_cols, wi_val,
                                        flagsR, x2list, tails + 2, e4);
    markB<<<scanGrid, blk, 0, stream>>>((const int4*)w_rows, w_cols, flagsR, flagN1, e4);
    markC_wi<<<scanGrid, blk, 0, stream>>>((const int4*)wi_rows, wi_cols, wi_val, diag1,
                                           flagN1, flagsR, wi_cnt, wi_rc, wi_cf,
                                           tails + 1, e4);
    whist<<<scanGrid, blk, 0, stream>>>((const int4*)w_rows, flagsR, w_cnt, w_compact,
                                        tails + 0, e4);
    {
        int nBlocks = (R + 255) / 256 + (N + 255) / 256;
        assign_offsets2<<<nBlocks, 256, 0, stream>>>(w_cnt, R, w_off, wi_cnt, N, wi_off, gcur);
    }
    place_fused<<<512, blk, 0, stream>>>(w_compact, tails + 0, w_cols, w_val, w_off, w_cur,
                                         wi_rc, wi_cf, tails + 1, wi_off, wi_cur,
                                         w_pairs, wi_pairs);

    // ---- layer 1 ----
    gemm1_kernel<<<dim3((N + blk - 1) / blk, B), blk, 0, stream>>>(x, W1, h1);
    gather_rows<32, 2><<<((size_t)R * 32 + blk - 1) / blk, blk, 0, stream>>>(
        h1, treg, w_off, w_cnt, w_pairs, flagsR, R);                  // t1 (overwrites compact)
    gather_rows<32, 0><<<((size_t)N * 32 + blk - 1) / blk, blk, 0, stream>>>(
        treg, x1, wi_off, wi_cnt, wi_pairs, flagN1, N);               // x1 (diag1 in coef)

    // ---- layer 2 ----
    gemm2_kernel<<<(N * B + blk - 1) / blk, blk, 0, stream>>>(x1, W2, h2, flagN1);
    gather_rows<16, 1><<<((size_t)R * 16 + blk - 1) / blk, blk, 0, stream>>>(
        h2, t2, w_off, w_cnt, w_pairs, flagsR, R);                    // t2
    x2final_heads<<<1, 64, 0, stream>>>(t2, x2list, tails + 2, diag2,
                                        rw1, rb1, rw2, rb2, out);
}

// Round 6
// 302.054 us; speedup vs baseline: 2.4839x; 2.4839x over previous
//
#include <hip/hip_runtime.h>

#define NEG_SLOPE 0.2f

static const int B = 4, N = 50000, R = 100000, E = 1600000;
static const int WI_CAP = 131072;   // wi pairs capacity (expected ~33k)
static const int X2_CAP = 4096;     // x2 edge list capacity (expected ~64)
static const int I4PB = 512;        // int4 groups per block in staged scans (2048 edges)

// flagsR bits: 1 = R2 (rows needed for t2), 2 = R1 (rows needed for t1)

// ---------- markA: wi edges with row >= N-2 -> flagsR bit0 + x2 edge list ------
__global__ void markA(const int4* __restrict__ wi_rows4, const int* __restrict__ wi_cols,
                      const float* __restrict__ wi_val,
                      int* __restrict__ flagsR, int2* __restrict__ x2list,
                      int* __restrict__ x2tail, int e4) {
    int base = blockIdx.x * (blockDim.x * 4) + threadIdx.x;
#pragma unroll
    for (int k = 0; k < 4; ++k) {
        int i = base + k * blockDim.x;
        if (i >= e4) continue;
        int4 r = wi_rows4[i];
        int rr[4] = {r.x, r.y, r.z, r.w};
#pragma unroll
        for (int j = 0; j < 4; ++j) {
            if (rr[j] >= N - 2) {
                int ed = i * 4 + j;
                int col = wi_cols[ed];
                flagsR[col] = 1;
                int pos = atomicAdd(x2tail, 1);   // ~64 total: negligible
                if (pos < X2_CAP)
                    x2list[pos] = make_int2(col * 2 + (rr[j] - (N - 2)),
                                            __float_as_int(wi_val[ed]));
            }
        }
    }
}

// ---------- markB: w edges with flagged row -> flagN1[col] ----------
__global__ void markB(const int4* __restrict__ w_rows4, const int* __restrict__ w_cols,
                      const int* __restrict__ flagsR, int* __restrict__ flagN1, int e4) {
    int base = blockIdx.x * (blockDim.x * 4) + threadIdx.x;
#pragma unroll
    for (int k = 0; k < 4; ++k) {
        int i = base + k * blockDim.x;
        if (i >= e4) continue;
        int4 r = w_rows4[i];
        int rr[4] = {r.x, r.y, r.z, r.w};
#pragma unroll
        for (int j = 0; j < 4; ++j)
            if (flagsR[rr[j]]) flagN1[w_cols[i * 4 + j]] = 1;
    }
}

// ---- markC_wi: wi edges with flagN1 row -> flagsR bit1, wi hist, staged compact --
// Block-staged compaction: LDS records, ONE global tail atomic per block.
__global__ void markC_wi(const int4* __restrict__ wi_rows4, const int* __restrict__ wi_cols,
                         const float* __restrict__ wi_val, const float* __restrict__ diag1,
                         const int* __restrict__ flagN1,
                         int* __restrict__ flagsR, int* __restrict__ wi_cnt,
                         int2* __restrict__ wi_rc, float* __restrict__ wi_cf,
                         int* __restrict__ witail, int e4) {
    __shared__ int lcount, gbase;
    __shared__ int2 srec[2048];
    __shared__ float scf[2048];
    if (threadIdx.x == 0) lcount = 0;
    __syncthreads();
    int lane = threadIdx.x & 63;
#pragma unroll
    for (int k = 0; k < 2; ++k) {
        int i = blockIdx.x * I4PB + k * 256 + threadIdx.x;
        int4 r = make_int4(-1, -1, -1, -1);
        if (i < e4) r = wi_rows4[i];
        int rr[4] = {r.x, r.y, r.z, r.w};
#pragma unroll
        for (int j = 0; j < 4; ++j) {
            bool pass = (rr[j] >= 0) && (flagN1[rr[j]] != 0);
            int col = 0; float cf = 0.f;
            if (pass) {
                int ed = i * 4 + j;
                col = wi_cols[ed];
                cf = wi_val[ed] * diag1[col];
                atomicAdd(&wi_cnt[rr[j]], 1);     // distributed: fine
                flagsR[col] |= 2;                 // benign same-value race
            }
            unsigned long long m = __ballot(pass);
            if (m) {
                int leader = __ffsll((unsigned long long)m) - 1;
                int b0 = 0;
                if (lane == leader) b0 = atomicAdd(&lcount, __popcll(m));  // LDS atomic
                b0 = __shfl(b0, leader);
                if (pass) {
                    int pos = b0 + __popcll(m & ((1ull << lane) - 1));
                    srec[pos] = make_int2(rr[j], col);
                    scf[pos] = cf;
                }
            }
        }
    }
    __syncthreads();
    if (threadIdx.x == 0) gbase = atomicAdd(witail, lcount);  // ONE per block
    __syncthreads();
    int n = lcount, gb = gbase;
    for (int t = threadIdx.x; t < n; t += blockDim.x) {
        int g = gb + t;
        if (g < WI_CAP) { wi_rc[g] = srec[t]; wi_cf[g] = scf[t]; }
    }
}

// ---------- whist: w edges with flagsR row -> w hist + staged (row,col,val) ------
__global__ void whist(const int4* __restrict__ w_rows4, const int* __restrict__ w_cols,
                      const float* __restrict__ w_val, const int* __restrict__ flagsR,
                      int* __restrict__ w_cnt, int2* __restrict__ w_srec,
                      float* __restrict__ w_sval, int* __restrict__ wtail, int e4) {
    __shared__ int lcount, gbase;
    __shared__ int2 srec[2048];
    __shared__ float sval[2048];
    if (threadIdx.x == 0) lcount = 0;
    __syncthreads();
    int lane = threadIdx.x & 63;
#pragma unroll
    for (int k = 0; k < 2; ++k) {
        int i = blockIdx.x * I4PB + k * 256 + threadIdx.x;
        int4 r = make_int4(-1, -1, -1, -1);
        if (i < e4) r = w_rows4[i];
        int rr[4] = {r.x, r.y, r.z, r.w};
#pragma unroll
        for (int j = 0; j < 4; ++j) {
            bool pass = (rr[j] >= 0) && (flagsR[rr[j]] != 0);
            int col = 0; float v = 0.f;
            if (pass) {
                int ed = i * 4 + j;
                col = w_cols[ed];
                v = w_val[ed];
                atomicAdd(&w_cnt[rr[j]], 1);      // distributed: fine
            }
            unsigned long long m = __ballot(pass);
            if (m) {
                int leader = __ffsll((unsigned long long)m) - 1;
                int b0 = 0;
                if (lane == leader) b0 = atomicAdd(&lcount, __popcll(m));  // LDS atomic
                b0 = __shfl(b0, leader);
                if (pass) {
                    int pos = b0 + __popcll(m & ((1ull << lane) - 1));
                    srec[pos] = make_int2(rr[j], col);
                    sval[pos] = v;
                }
            }
        }
    }
    __syncthreads();
    if (threadIdx.x == 0) gbase = atomicAdd(wtail, lcount);   // ONE per block
    __syncthreads();
    int n = lcount, gb = gbase;
    for (int t = threadIdx.x; t < n; t += blockDim.x) {
        w_srec[gb + t] = srec[t];
        w_sval[gb + t] = sval[t];
    }
}

// ------- segment base assignment for both CSRs in one dispatch (order-free) -----
__global__ void assign_offsets2(const int* __restrict__ cntA, int nA, int* __restrict__ offA,
                                const int* __restrict__ cntB, int nB, int* __restrict__ offB,
                                int* __restrict__ gcur) {
    int nBlocksA = (nA + 255) / 256;
    bool isA = (int)blockIdx.x < nBlocksA;
    const int* cnt = isA ? cntA : cntB;
    int* off = isA ? offA : offB;
    int n = isA ? nA : nB;
    int* gc = gcur + (isA ? 0 : 1);
    int blk = isA ? blockIdx.x : (blockIdx.x - nBlocksA);
    int i = blk * 256 + threadIdx.x;
    int tid = threadIdx.x;
    int v = (i < n) ? cnt[i] : 0;
    __shared__ int s[256];
    s[tid] = v;
    __syncthreads();
#pragma unroll
    for (int d = 1; d < 256; d <<= 1) {
        int t = (tid >= d) ? s[tid - d] : 0;
        __syncthreads();
        s[tid] += t;
        __syncthreads();
    }
    int incl = s[tid];
    __shared__ int base;
    if (tid == 255) base = atomicAdd(gc, incl);
    __syncthreads();
    if (i < n) off[i] = base + incl - v;
}

// ---------- place both CSRs from staged records (linear reads, grid-stride) ------
__global__ void place_fused(const int2* __restrict__ w_srec, const float* __restrict__ w_sval,
                            const int* __restrict__ wtail,
                            const int* __restrict__ w_off, int* __restrict__ w_cur,
                            const int2* __restrict__ wi_rc, const float* __restrict__ wi_cf,
                            const int* __restrict__ witail,
                            const int* __restrict__ wi_off, int* __restrict__ wi_cur,
                            int2* __restrict__ w_pairs, int2* __restrict__ wi_pairs) {
    int wt = *wtail;
    int wit = *witail; if (wit > WI_CAP) wit = WI_CAP;
    int total = wt + wit;
    int stride = gridDim.x * blockDim.x;
    for (int i = blockIdx.x * blockDim.x + threadIdx.x; i < total; i += stride) {
        if (i < wt) {
            int2 rc = w_srec[i];
            int pos = w_off[rc.x] + atomicAdd(&w_cur[rc.x], 1);
            w_pairs[pos] = make_int2(rc.y, __float_as_int(w_sval[i]));
        } else {
            int j = i - wt;
            int2 rc = wi_rc[j];
            int pos = wi_off[rc.x] + atomicAdd(&wi_cur[rc.x], 1);
            wi_pairs[pos] = make_int2(rc.y, __float_as_int(wi_cf[j]));
        }
    }
}

// ---------- gemm1: x [B][N][32] -> h1 [N][B][32] ----------
__global__ void gemm1_kernel(const float* __restrict__ x, const float* __restrict__ W,
                             float* __restrict__ h1) {
    __shared__ float sW[32 * 32];
    for (int i = threadIdx.x; i < 32 * 32; i += blockDim.x) sW[i] = W[i];
    __syncthreads();
    int n = blockIdx.x * blockDim.x + threadIdx.x;
    int b = blockIdx.y;
    if (n >= N) return;
    const float* xr = x + ((size_t)b * N + n) * 32;
    float acc[32];
#pragma unroll
    for (int c = 0; c < 32; ++c) acc[c] = 0.f;
#pragma unroll
    for (int k = 0; k < 32; ++k) {
        float xv = xr[k];
#pragma unroll
        for (int c = 0; c < 32; ++c) acc[c] += xv * sW[k * 32 + c];
    }
    float* o = h1 + ((size_t)n * B + b) * 32;
#pragma unroll
    for (int c = 0; c < 32; ++c) o[c] = acc[c];
}

// ---------- gemm2: x1 [N][B][32] (lrelu) -> h2 [N][B][16], flagN1-gated ----------
__global__ void gemm2_kernel(const float* __restrict__ x1, const float* __restrict__ W,
                             float* __restrict__ h2, const int* __restrict__ flagN1) {
    __shared__ float sW[32 * 16];
    for (int i = threadIdx.x; i < 32 * 16; i += blockDim.x) sW[i] = W[i];
    __syncthreads();
    int id = blockIdx.x * blockDim.x + threadIdx.x;   // n*B + b
    if (id >= N * B) return;
    if (!flagN1[id >> 2]) return;
    const float* xr = x1 + (size_t)id * 32;
    float acc[16];
#pragma unroll
    for (int c = 0; c < 16; ++c) acc[c] = 0.f;
#pragma unroll
    for (int k = 0; k < 32; ++k) {
        float xv = xr[k];
        xv = xv > 0.f ? xv : NEG_SLOPE * xv;
#pragma unroll
        for (int c = 0; c < 16; ++c) acc[c] += xv * sW[k * 16 + c];
    }
    float* o = h2 + (size_t)id * 16;
#pragma unroll
    for (int c = 0; c < 16; ++c) o[c] = acc[c];
}

// ---- flag-gated CSR gather, batch-inner layout [node][B][C], float4/thread ----
template<int C, int FLAGBIT>
__global__ void gather_rows(const float* __restrict__ src, float* __restrict__ dst,
                            const int* __restrict__ off, const int* __restrict__ len,
                            const int2* __restrict__ pairs, const int* __restrict__ flag,
                            int nRows) {
    constexpr int C4 = C / 4;
    constexpr int TPR = C4 * B;
    constexpr int STRIDE = B * C4;        // float4 stride per source node block
    int tid = blockIdx.x * blockDim.x + threadIdx.x;
    int row = tid / TPR;
    int rem = tid - row * TPR;
    int c4 = rem & (C4 - 1);
    int b  = rem / C4;
    if (row >= nRows) return;
    int f = flag[row];
    if (FLAGBIT ? !(f & FLAGBIT) : !f) return;
    int s = off[row];
    int L = len[row];
    const float4* sb = (const float4*)src + b * C4 + c4;
    float4 acc = make_float4(0.f, 0.f, 0.f, 0.f);
    int i = s;
    int e4i = s + (L & ~3);
    for (; i < e4i; i += 4) {
        int2 p0 = pairs[i + 0];
        int2 p1 = pairs[i + 1];
        int2 p2 = pairs[i + 2];
        int2 p3 = pairs[i + 3];
        float4 s0 = sb[(size_t)p0.x * STRIDE];
        float4 s1 = sb[(size_t)p1.x * STRIDE];
        float4 s2 = sb[(size_t)p2.x * STRIDE];
        float4 s3 = sb[(size_t)p3.x * STRIDE];
        float v0 = __int_as_float(p0.y), v1 = __int_as_float(p1.y);
        float v2 = __int_as_float(p2.y), v3 = __int_as_float(p3.y);
        acc.x += v0 * s0.x + v1 * s1.x + v2 * s2.x + v3 * s3.x;
        acc.y += v0 * s0.y + v1 * s1.y + v2 * s2.y + v3 * s3.y;
        acc.z += v0 * s0.z + v1 * s1.z + v2 * s2.z + v3 * s3.z;
        acc.w += v0 * s0.w + v1 * s1.w + v2 * s2.w + v3 * s3.w;
    }
    for (; i < s + L; ++i) {
        int2 p = pairs[i];
        float4 sv = sb[(size_t)p.x * STRIDE];
        float v = __int_as_float(p.y);
        acc.x += v * sv.x; acc.y += v * sv.y; acc.z += v * sv.z; acc.w += v * sv.w;
    }
    ((float4*)dst)[(size_t)row * STRIDE + b * C4 + c4] = acc;
}

// ---------- x2 accumulation (tiny list) + heads, single block ----------
__global__ void x2final_heads(const float* __restrict__ t2, const int2* __restrict__ x2list,
                              const int* __restrict__ x2tail, const float* __restrict__ diag2,
                              const float* __restrict__ rw1, const float* __restrict__ rb1,
                              const float* __restrict__ rw2, const float* __restrict__ rb2,
                              float* __restrict__ out) {
    __shared__ float s[2 * B * 16];
    int tid = threadIdx.x;                // 64 threads: b = tid>>4, c = tid&15
    int b = tid >> 4, c = tid & 15;
    float acc0 = 0.f, acc1 = 0.f;
    int cnt = *x2tail; if (cnt > X2_CAP) cnt = X2_CAP;
    for (int i = 0; i < cnt; ++i) {
        int2 rec = x2list[i];
        int col = rec.x >> 1;
        float coef = __int_as_float(rec.y) * diag2[col];
        float v = t2[((size_t)col * B + b) * 16 + c] * coef;
        if (rec.x & 1) acc1 += v; else acc0 += v;
    }
    s[(b * 2 + 0) * 16 + c] = acc0;
    s[(b * 2 + 1) * 16 + c] = acc1;
    __syncthreads();
    if (tid < 2 * B) {
        int bb = tid >> 1, which = tid & 1;
        const float* w = which ? rw2 : rw1;
        float acc = which ? rb2[0] : rb1[0];
        const float* xr = s + (bb * 2 + which) * 16;
        for (int k = 0; k < 16; ++k) {
            float xv = xr[k];
            xv = xv > 0.f ? xv : NEG_SLOPE * xv;
            acc += xv * w[k];
        }
        out[tid] = acc;
    }
}

extern "C" void kernel_launch(void* const* d_in, const int* in_sizes, int n_in,
                              void* d_out, int out_size, void* d_ws, size_t ws_size,
                              hipStream_t stream) {
    const int*   w_rows  = (const int*)d_in[0];
    const int*   w_cols  = ((const int*)d_in[0]) + E;
    const float* w_val   = (const float*)d_in[1];
    const int*   wi_rows = (const int*)d_in[2];
    const int*   wi_cols = ((const int*)d_in[2]) + E;
    const float* wi_val  = (const float*)d_in[3];
    const float* x       = (const float*)d_in[4];
    const float* W1      = (const float*)d_in[5];
    const float* diag1   = (const float*)d_in[6];
    const float* W2      = (const float*)d_in[7];
    const float* diag2   = (const float*)d_in[8];
    const float* rw1     = (const float*)d_in[9];
    const float* rb1     = (const float*)d_in[10];
    const float* rw2     = (const float*)d_in[11];
    const float* rb2     = (const float*)d_in[12];
    float* out = (float*)d_out;

    // ---------------- workspace layout ----------------
    float* h1   = (float*)d_ws;                 // [N][B][32]; later aliased as x1
    float* treg = h1 + (size_t)B * N * 32;      // 12.8M floats: staging early; t1/h2/t2 later
    int* ip = (int*)(treg + (size_t)B * R * 32);
    // zeroed block:
    int* w_cnt  = ip; ip += R;
    int* w_off  = ip; ip += R;
    int* w_cur  = ip; ip += R;
    int* wi_cnt = ip; ip += N;
    int* wi_off = ip; ip += N;
    int* wi_cur = ip; ip += N;
    int* flagsR = ip; ip += R;
    int* flagN1 = ip; ip += N;
    int* gcur   = ip; ip += 2;
    int* tails  = ip; ip += 4;   // [0]=wtail [1]=witail [2]=x2tail
    size_t zero_words = (size_t)(ip - w_cnt);
    // un-zeroed:
    int2* w_pairs  = (int2*)ip; ip += 2 * E;
    int2* wi_pairs = (int2*)ip; ip += 2 * WI_CAP;
    int2* x2list   = (int2*)ip; ip += 2 * X2_CAP;
    // staging buffers aliased inside treg (dead before t1 is written):
    int2*  w_srec = (int2*)treg;                                   // up to E
    float* w_sval = treg + (size_t)2 * E;                          // up to E
    int2*  wi_rc  = (int2*)(treg + (size_t)3 * E);                 // WI_CAP
    float* wi_cf  = treg + (size_t)3 * E + (size_t)2 * WI_CAP;     // WI_CAP

    float* x1 = h1;                          // alias
    float* h2 = treg;                        // [N][B][16]
    float* t2 = treg + (size_t)B * N * 16;   // [R][B][16]

    const int blk = 256;
    const int e4 = E / 4;
    const int markGrid = (e4 + blk * 4 - 1) / (blk * 4);
    const int stageGrid = (e4 + I4PB - 1) / I4PB;

    hipMemsetAsync(w_cnt, 0, zero_words * sizeof(int), stream);

    // ---- frontier + CSR build ----
    markA<<<markGrid, blk, 0, stream>>>((const int4*)wi_rows, wi_cols, wi_val,
                                        flagsR, x2list, tails + 2, e4);
    markB<<<markGrid, blk, 0, stream>>>((const int4*)w_rows, w_cols, flagsR, flagN1, e4);
    markC_wi<<<stageGrid, blk, 0, stream>>>((const int4*)wi_rows, wi_cols, wi_val, diag1,
                                            flagN1, flagsR, wi_cnt, wi_rc, wi_cf,
                                            tails + 1, e4);
    whist<<<stageGrid, blk, 0, stream>>>((const int4*)w_rows, w_cols, w_val, flagsR,
                                         w_cnt, w_srec, w_sval, tails + 0, e4);
    {
        int nBlocks = (R + 255) / 256 + (N + 255) / 256;
        assign_offsets2<<<nBlocks, 256, 0, stream>>>(w_cnt, R, w_off, wi_cnt, N, wi_off, gcur);
    }
    place_fused<<<512, blk, 0, stream>>>(w_srec, w_sval, tails + 0, w_off, w_cur,
                                         wi_rc, wi_cf, tails + 1, wi_off, wi_cur,
                                         w_pairs, wi_pairs);

    // ---- layer 1 ----
    gemm1_kernel<<<dim3((N + blk - 1) / blk, B), blk, 0, stream>>>(x, W1, h1);
    gather_rows<32, 2><<<((size_t)R * 32 + blk - 1) / blk, blk, 0, stream>>>(
        h1, treg, w_off, w_cnt, w_pairs, flagsR, R);                  // t1 (overwrites staging)
    gather_rows<32, 0><<<((size_t)N * 32 + blk - 1) / blk, blk, 0, stream>>>(
        treg, x1, wi_off, wi_cnt, wi_pairs, flagN1, N);               // x1 (diag1 in coef)

    // ---- layer 2 ----
    gemm2_kernel<<<(N * B + blk - 1) / blk, blk, 0, stream>>>(x1, W2, h2, flagN1);
    gather_rows<16, 1><<<((size_t)R * 16 + blk - 1) / blk, blk, 0, stream>>>(
        h2, t2, w_off, w_cnt, w_pairs, flagsR, R);                    // t2
    x2final_heads<<<1, 64, 0, stream>>>(t2, x2list, tails + 2, diag2,
                                        rw1, rb1, rw2, rb2, out);
}